// Round 11
// baseline (157.910 us; speedup 1.0000x reference)
//
#include <hip/hip_runtime.h>
#include <hip/hip_bf16.h>

#define B_  2
#define T_  2048
#define D_  1024
#define H_  16
#define DH_ 64
#define M_  (B_ * T_)   // 4096 rows

typedef short s16x8 __attribute__((ext_vector_type(8)));
typedef float f32x4 __attribute__((ext_vector_type(4)));

__device__ inline float bfu(unsigned short u) {
    union { unsigned int i; float f; } c; c.i = ((unsigned int)u) << 16; return c.f;
}
__device__ inline unsigned short f2bf(float f) {   // round-to-nearest-even
    union { float f; unsigned int i; } c; c.f = f;
    unsigned int r = c.i + 0x7fffu + ((c.i >> 16) & 1u);
    return (unsigned short)(r >> 16);
}
__device__ inline void stv(float* p, float v) { *p = v; }
__device__ inline void stv(unsigned short* p, float v) { *p = f2bf(v); }

// async global->LDS, 16B per lane; lds base must be wave-uniform (HW adds lane*16)
__device__ inline void gload_lds16(const unsigned short* g, unsigned short* l) {
    __builtin_amdgcn_global_load_lds(
        (const __attribute__((address_space(1))) void*)g,
        (__attribute__((address_space(3))) void*)l, 16, 0, 0);
}

// ---------------------------------------------------------------------------
// fp32 -> bf16 conversion of x and the 4 weights into one contiguous ws blob.
// ---------------------------------------------------------------------------
__global__ __launch_bounds__(256) void conv_bf16(const float* __restrict__ x,
                                                 const float* __restrict__ Wq,
                                                 const float* __restrict__ Wk,
                                                 const float* __restrict__ Wv,
                                                 const float* __restrict__ Wo,
                                                 unsigned short* __restrict__ dst) {
    const int g = blockIdx.x * 256 + threadIdx.x;       // 0 .. 2^21-1
    const float* s; size_t o;
    if (g < (1 << 20)) { s = x; o = (size_t)g; }
    else {
        int gg = g - (1 << 20);
        int w = gg >> 18;
        o = (size_t)(gg & ((1 << 18) - 1));
        s = (w == 0) ? Wq : (w == 1) ? Wk : (w == 2) ? Wv : Wo;
    }
    float4 v = ((const float4*)s)[o];
    ushort4 u;
    u.x = f2bf(v.x); u.y = f2bf(v.y); u.z = f2bf(v.z); u.w = f2bf(v.w);
    ((ushort4*)dst)[g] = u;
}

// ---------------------------------------------------------------------------
// m97-style MFMA NT GEMM, BK = 32*NH stacked half-tiles. BM x BN tile,
// 256 thr (2x2 waves of (BM/2)x(BN/2)), 16x16x32 MFMA, fp32 acc.
// Staging: global_load_lds width=16, unpadded 32-ushort LDS rows.
// Output: row stride 1024, buffer per n-tile: bn<1024 -> C0, bn<2048 -> C1,
// bn>=2048 (only when vtr != null) -> V written TRANSPOSED to
// vtr[(b*16+h)*64+d][t] (packed ushort4: r = 4 consecutive t).
// ---------------------------------------------------------------------------
template <int BM, int BN, int NH, typename Tout>
__global__ __launch_bounds__(256) void gemm_m97(const unsigned short* __restrict__ A,
                                                const unsigned short* __restrict__ Bw,
                                                Tout* __restrict__ C0,
                                                Tout* __restrict__ C1,
                                                unsigned short* __restrict__ vtr,
                                                int K) {
    constexpr int MI = BM / 32;                   // m-frags per wave
    constexpr int NI = BN / 32;                   // n-frags per wave
    __shared__ unsigned short As[NH * BM * 32];
    __shared__ unsigned short Bs[NH * BN * 32];
    const int tid  = threadIdx.x;
    const int lane = tid & 63;
    const int wave = tid >> 6;
    const int wr = wave >> 1, wc = wave & 1;
    const int bm = blockIdx.y * BM, bn = blockIdx.x * BN;
    const int fr = lane & 15, kg = lane >> 4;
    const int lrow = lane >> 2;          // staging row within 16-row window
    const int lcol = (lane & 3) * 8;     // staging 16B chunk (ushort offset)

    f32x4 acc[MI][NI];
    #pragma unroll
    for (int mi = 0; mi < MI; ++mi)
        #pragma unroll
        for (int ni = 0; ni < NI; ++ni)
            #pragma unroll
            for (int r = 0; r < 4; ++r) acc[mi][ni][r] = 0.f;

    const unsigned short* ga = A  + (size_t)(bm + wave * 16 + lrow) * K + lcol;
    const unsigned short* gb = Bw + (size_t)(bn + wave * 16 + lrow) * K + lcol;
    unsigned short* la = &As[(wave * 16) * 32];   // wave-uniform
    unsigned short* lb = &Bs[(wave * 16) * 32];

    for (int k0 = 0; k0 < K; k0 += 32 * NH) {
        __syncthreads();                          // prev-iter LDS reads done
        #pragma unroll
        for (int hf = 0; hf < NH; ++hf) {
            #pragma unroll
            for (int s = 0; s < BM / 64; ++s)
                gload_lds16(ga + k0 + hf * 32 + (size_t)(s * 64) * K,
                            la + hf * BM * 32 + s * 64 * 32);
            #pragma unroll
            for (int s = 0; s < BN / 64; ++s)
                gload_lds16(gb + k0 + hf * 32 + (size_t)(s * 64) * K,
                            lb + hf * BN * 32 + s * 64 * 32);
        }
        __syncthreads();                          // vmcnt drained: tile visible
        #pragma unroll
        for (int hf = 0; hf < NH; ++hf) {
            s16x8 af[MI], bfv[NI];
            #pragma unroll
            for (int mi = 0; mi < MI; ++mi)
                af[mi] = *(const s16x8*)&As[hf * BM * 32 + (wr * (BM / 2) + mi * 16 + fr) * 32 + kg * 8];
            #pragma unroll
            for (int ni = 0; ni < NI; ++ni)
                bfv[ni] = *(const s16x8*)&Bs[hf * BN * 32 + (wc * (BN / 2) + ni * 16 + fr) * 32 + kg * 8];
            #pragma unroll
            for (int mi = 0; mi < MI; ++mi)
                #pragma unroll
                for (int ni = 0; ni < NI; ++ni)
                    acc[mi][ni] = __builtin_amdgcn_mfma_f32_16x16x32_bf16(af[mi], bfv[ni], acc[mi][ni], 0, 0, 0);
        }
    }

    if (vtr && bn >= 2048) {
        // V n-tile: write transposed, packed over r (4 consecutive t)
        #pragma unroll
        for (int mi = 0; mi < MI; ++mi)
            #pragma unroll
            for (int ni = 0; ni < NI; ++ni) {
                const int nl = (bn - 2048) + wc * (BN / 2) + ni * 16 + fr;
                const int h = nl >> 6, d = nl & 63;
                const int m0 = bm + wr * (BM / 2) + mi * 16 + kg * 4;
                const int b = m0 >> 11, t0 = m0 & (T_ - 1);
                ushort4 u;
                u.x = f2bf(acc[mi][ni][0]); u.y = f2bf(acc[mi][ni][1]);
                u.z = f2bf(acc[mi][ni][2]); u.w = f2bf(acc[mi][ni][3]);
                *(ushort4*)(vtr + ((size_t)(b * H_ + h) * 64 + d) * T_ + t0) = u;
            }
        return;
    }
    Tout* C = (bn < 1024) ? C0 : C1;
    const int nb = bn & 1023;
    #pragma unroll
    for (int mi = 0; mi < MI; ++mi)
        #pragma unroll
        for (int ni = 0; ni < NI; ++ni)
            #pragma unroll
            for (int r = 0; r < 4; ++r) {
                int m = bm + wr * (BM / 2) + mi * 16 + kg * 4 + r;
                int n = nb + wc * (BN / 2) + ni * 16 + fr;
                stv(&C[(size_t)m * 1024 + n], acc[mi][ni][r]);
            }
}

// ---------------------------------------------------------------------------
// MFMA sliding-window attention v4. Block = 64 queries of one (b,h).
// K window [klo2,+192) and V^T window [klo2,+208) staged via global_load_lds
// with XOR chunk swizzle (validated r10). NEW: P reuses the Ks LDS region
// (barrier after QK^T when Ks is dead) -> 50 KB/block -> 3 blocks/CU.
// o==q in-place safe (wave-private rows).
// ---------------------------------------------------------------------------
__global__ __launch_bounds__(256) void swa_mfma4(const unsigned short* qb,
                                                 const unsigned short* __restrict__ kb,
                                                 const unsigned short* __restrict__ vt,
                                                 unsigned short* ob) {
    __shared__ unsigned short Ks[192 * 64];        // 24 KB; P lives here later
    __shared__ unsigned short Vs[64 * 208];        // 26 KB, swizzled (c<24)
    const int wave = threadIdx.x >> 6;
    const int lane = threadIdx.x & 63;
    const int blk = blockIdx.x;                    // 0..1023
    const int i0b = (blk & 31) * 64;               // block's first query
    const int bh  = blk >> 5;
    const int h = bh & (H_ - 1), b = bh >> 4;
    const int g = lane >> 4, l15 = lane & 15;

    const size_t rowbase = (size_t)b * T_ * D_ + (size_t)h * DH_;
    const int klo2 = (i0b > 128) ? (i0b - 128) : 0;   // <= 1856

    // ---- stage K rows [klo2, +192), XOR-swizzled chunks ----
    {
        const int lr = lane >> 3;                  // 0..7
        const int gc = (lane & 7) ^ lr;            // global chunk to fetch
        const unsigned short* kg0 = kb + rowbase + (size_t)(klo2 + lr) * D_ + gc * 8;
        #pragma unroll
        for (int s = 0; s < 6; ++s) {
            const int i = wave * 6 + s;            // 24 instrs, 8 rows each
            gload_lds16(kg0 + (size_t)(i * 8) * D_, &Ks[i * 8 * 64]);
        }
    }
    // ---- stage V^T rows d=0..63, cols [klo2, +208), 26 chunks/row ----
    {
        const unsigned short* vtb = vt + (size_t)bh * 64 * T_ + klo2;
        #pragma unroll
        for (int s = 0; s < 7; ++s) {
            const int i = s * 4 + wave;            // wave-uniform
            if (i < 26) {
                const int cc = i * 64 + lane;      // flat chunk 0..1663
                const int d  = cc / 26;
                const int sl = cc - d * 26;        // LDS slot 0..25
                const int c  = (sl < 24) ? (sl ^ (d & 7)) : sl;  // global chunk
                gload_lds16(vtb + (size_t)d * T_ + c * 8, &Vs[i * 512]);
            }
        }
    }

    const int i0  = i0b + wave * 16;
    const int klo = (i0 > 128) ? (i0 - 128) : 0;
    const int koff = klo - klo2;                   // 0,16,32,48

    // Q fragments from global (overlaps with staging drain)
    const unsigned short* qrow = qb + rowbase + (size_t)(i0 + l15) * D_ + g * 8;
    const s16x8 aq0 = *(const s16x8*)(qrow);
    const s16x8 aq1 = *(const s16x8*)(qrow + 32);

    __syncthreads();                               // K+V windows visible

    // ---- S = Q K^T over 9 key tiles (B-frags from swizzled Ks) ----
    f32x4 sacc[9];
    #pragma unroll
    for (int t = 0; t < 9; ++t)
        #pragma unroll
        for (int r = 0; r < 4; ++r) sacc[t][r] = 0.f;

    #pragma unroll
    for (int t = 0; t < 9; ++t) {
        const int row = koff + t * 16 + l15;       // <= 191
        const int r7 = row & 7;
        s16x8 b0 = *(const s16x8*)&Ks[row * 64 + ((g     ^ r7) * 8)];
        s16x8 b1 = *(const s16x8*)&Ks[row * 64 + (((g+4) ^ r7) * 8)];
        sacc[t] = __builtin_amdgcn_mfma_f32_16x16x32_bf16(aq0, b0, sacc[t], 0, 0, 0);
        sacc[t] = __builtin_amdgcn_mfma_f32_16x16x32_bf16(aq1, b1, sacc[t], 0, 0, 0);
    }

    __syncthreads();                               // Ks dead -> P may reuse it
    unsigned short* Pw = &Ks[wave * (16 * 168)];   // 4 x 5376 B, 16B-aligned
    {   // zero-pad P cols 144..159 (read by last PV k-tile)
        int row = lane >> 2, col = 144 + (lane & 3) * 4;
        *(uint2*)&Pw[row * 168 + col] = make_uint2(0u, 0u);
    }

    // ---- mask + scale + softmax (C/D layout: row g*4+r, col l15) ----
    float mrow[4] = {-1e30f, -1e30f, -1e30f, -1e30f};
    #pragma unroll
    for (int t = 0; t < 9; ++t)
        #pragma unroll
        for (int r = 0; r < 4; ++r) {
            const int j  = klo + t * 16 + l15;
            const int iq = i0 + g * 4 + r;
            const bool valid = (j <= iq) && (j + 128 >= iq);
            const float s = valid ? sacc[t][r] * 0.125f : -1e30f;
            sacc[t][r] = s;
            mrow[r] = fmaxf(mrow[r], s);
        }
    #pragma unroll
    for (int r = 0; r < 4; ++r)
        #pragma unroll
        for (int off = 1; off < 16; off <<= 1)
            mrow[r] = fmaxf(mrow[r], __shfl_xor(mrow[r], off));

    float lrow[4] = {0.f, 0.f, 0.f, 0.f};
    #pragma unroll
    for (int t = 0; t < 9; ++t)
        #pragma unroll
        for (int r = 0; r < 4; ++r) {
            const float p = __expf(sacc[t][r] - mrow[r]);
            sacc[t][r] = p;
            lrow[r] += p;
        }
    #pragma unroll
    for (int r = 0; r < 4; ++r) {
        #pragma unroll
        for (int off = 1; off < 16; off <<= 1)
            lrow[r] += __shfl_xor(lrow[r], off);
    }
    float invl[4];
    #pragma unroll
    for (int r = 0; r < 4; ++r) invl[r] = 1.f / lrow[r];

    // ---- P (bf16) -> per-wave LDS (same-wave write->read, no barrier) ----
    #pragma unroll
    for (int t = 0; t < 9; ++t)
        #pragma unroll
        for (int r = 0; r < 4; ++r)
            Pw[(g * 4 + r) * 168 + t * 16 + l15] = f2bf(sacc[t][r]);

    // ---- O = P V : A = P from LDS, B = V^T rows from swizzled Vs ----
    f32x4 oacc[4];
    #pragma unroll
    for (int nt = 0; nt < 4; ++nt)
        #pragma unroll
        for (int r = 0; r < 4; ++r) oacc[nt][r] = 0.f;

    const int kc0 = koff >> 3;                     // 0,2,4,6
    #pragma unroll
    for (int kt = 0; kt < 5; ++kt) {
        const s16x8 ap = *(const s16x8*)&Pw[l15 * 168 + kt * 32 + g * 8];
        #pragma unroll
        for (int nt = 0; nt < 4; ++nt) {
            const int d = nt * 16 + l15;
            const int c = kc0 + kt * 4 + g;        // global chunk 0..25
            const int sl = (c < 24) ? (c ^ (d & 7)) : c;
            s16x8 bv = *(const s16x8*)&Vs[d * 208 + sl * 8];
            oacc[nt] = __builtin_amdgcn_mfma_f32_16x16x32_bf16(ap, bv, oacc[nt], 0, 0, 0);
        }
    }

    #pragma unroll
    for (int nt = 0; nt < 4; ++nt)
        #pragma unroll
        for (int r = 0; r < 4; ++r) {
            const float val = oacc[nt][r] * invl[r];
            ob[rowbase + (size_t)(i0 + g * 4 + r) * D_ + nt * 16 + l15] = f2bf(val);
        }
}

extern "C" void kernel_launch(void* const* d_in, const int* in_sizes, int n_in,
                              void* d_out, int out_size, void* d_ws, size_t ws_size,
                              hipStream_t stream) {
    const float* x  = (const float*)d_in[0];
    const float* Wq = (const float*)d_in[1];
    const float* Wk = (const float*)d_in[2];
    const float* Wv = (const float*)d_in[3];
    const float* Wo = (const float*)d_in[4];

    const size_t MD = (size_t)M_ * D_;      // 4,194,304
    const size_t WN = (size_t)D_ * D_;      // 1,048,576

    // ws (bf16): xb | Wqb|Wkb|Wvb | Wob | qb  = 24 MB
    unsigned short* wsb = (unsigned short*)d_ws;
    unsigned short* xb  = wsb;
    unsigned short* Wqb = xb + MD;          // Wq|Wk|Wv adjacent = merged B matrix
    unsigned short* Wob = Wqb + 3 * WN;
    unsigned short* qb  = Wob + WN;
    // d_out doubles as vt | kb until the final GEMM overwrites it.
    // vt FIRST: swa's V-window tail over-reads land in kb, never past d_out.
    unsigned short* vt = (unsigned short*)d_out;
    unsigned short* kb = vt + MD;

    conv_bf16<<<8192, 256, 0, stream>>>(x, Wq, Wk, Wv, Wo, wsb);

    // merged QKV projection: N=3072, BN=64 -> 1536 blocks (6/CU); V transposed
    gemm_m97<128, 64, 2, unsigned short><<<dim3(48, M_ / 128), 256, 0, stream>>>(
        xb, Wqb, qb, kb, vt, D_);

    swa_mfma4<<<(B_ * H_ * T_) / 64, 256, 0, stream>>>(qb, kb, vt, qb);

    // output projection: N=1024, 64x64 tiles, BK=128 -> 1024 blocks (4/CU)
    gemm_m97<64, 64, 4, float><<<dim3(16, M_ / 64), 256, 0, stream>>>(
        qb, Wob, (float*)d_out, (float*)d_out, nullptr, D_);
}

// Round 12
// 149.294 us; speedup vs baseline: 1.0577x; 1.0577x over previous
//
#include <hip/hip_runtime.h>
#include <hip/hip_bf16.h>

#define B_  2
#define T_  2048
#define D_  1024
#define H_  16
#define DH_ 64
#define M_  (B_ * T_)   // 4096 rows

typedef short s16x8 __attribute__((ext_vector_type(8)));
typedef float f32x4 __attribute__((ext_vector_type(4)));

__device__ inline float bfu(unsigned short u) {
    union { unsigned int i; float f; } c; c.i = ((unsigned int)u) << 16; return c.f;
}
__device__ inline unsigned short f2bf(float f) {   // round-to-nearest-even
    union { float f; unsigned int i; } c; c.f = f;
    unsigned int r = c.i + 0x7fffu + ((c.i >> 16) & 1u);
    return (unsigned short)(r >> 16);
}
__device__ inline void stv(float* p, float v) { *p = v; }
__device__ inline void stv(unsigned short* p, float v) { *p = f2bf(v); }

// async global->LDS, 16B per lane; lds base must be wave-uniform (HW adds lane*16)
__device__ inline void gload_lds16(const unsigned short* g, unsigned short* l) {
    __builtin_amdgcn_global_load_lds(
        (const __attribute__((address_space(1))) void*)g,
        (__attribute__((address_space(3))) void*)l, 16, 0, 0);
}

// ---------------------------------------------------------------------------
// fp32 -> bf16 conversion of x and the 4 weights into one contiguous ws blob.
// ---------------------------------------------------------------------------
__global__ __launch_bounds__(256) void conv_bf16(const float* __restrict__ x,
                                                 const float* __restrict__ Wq,
                                                 const float* __restrict__ Wk,
                                                 const float* __restrict__ Wv,
                                                 const float* __restrict__ Wo,
                                                 unsigned short* __restrict__ dst) {
    const int g = blockIdx.x * 256 + threadIdx.x;       // 0 .. 2^21-1
    const float* s; size_t o;
    if (g < (1 << 20)) { s = x; o = (size_t)g; }
    else {
        int gg = g - (1 << 20);
        int w = gg >> 18;
        o = (size_t)(gg & ((1 << 18) - 1));
        s = (w == 0) ? Wq : (w == 1) ? Wk : (w == 2) ? Wv : Wo;
    }
    float4 v = ((const float4*)s)[o];
    ushort4 u;
    u.x = f2bf(v.x); u.y = f2bf(v.y); u.z = f2bf(v.z); u.w = f2bf(v.w);
    ((ushort4*)dst)[g] = u;
}

// ---------------------------------------------------------------------------
// m97-style MFMA NT GEMM, BK = 32*NH stacked half-tiles. BM x BN tile,
// 256 thr (2x2 waves of (BM/2)x(BN/2)), 16x16x32 MFMA, fp32 acc.
// Staging: global_load_lds width=16, unpadded 32-ushort LDS rows.
// NOTE (r11 lesson): keep >=32 MFMAs per barrier drain; BN=64 on the QKV
// GEMM regressed 40->46.7 us (16 MFMA/drain + 2x A-tile restage traffic).
// Output: row stride 1024, buffer per n-tile: bn<1024 -> C0, bn<2048 -> C1,
// bn>=2048 (only when vtr != null) -> V written TRANSPOSED to
// vtr[(b*16+h)*64+d][t] (packed ushort4: r = 4 consecutive t).
// ---------------------------------------------------------------------------
template <int BM, int BN, int NH, typename Tout>
__global__ __launch_bounds__(256) void gemm_m97(const unsigned short* __restrict__ A,
                                                const unsigned short* __restrict__ Bw,
                                                Tout* __restrict__ C0,
                                                Tout* __restrict__ C1,
                                                unsigned short* __restrict__ vtr,
                                                int K) {
    constexpr int MI = BM / 32;                   // m-frags per wave
    constexpr int NI = BN / 32;                   // n-frags per wave
    __shared__ unsigned short As[NH * BM * 32];
    __shared__ unsigned short Bs[NH * BN * 32];
    const int tid  = threadIdx.x;
    const int lane = tid & 63;
    const int wave = tid >> 6;
    const int wr = wave >> 1, wc = wave & 1;
    const int bm = blockIdx.y * BM, bn = blockIdx.x * BN;
    const int fr = lane & 15, kg = lane >> 4;
    const int lrow = lane >> 2;          // staging row within 16-row window
    const int lcol = (lane & 3) * 8;     // staging 16B chunk (ushort offset)

    f32x4 acc[MI][NI];
    #pragma unroll
    for (int mi = 0; mi < MI; ++mi)
        #pragma unroll
        for (int ni = 0; ni < NI; ++ni)
            #pragma unroll
            for (int r = 0; r < 4; ++r) acc[mi][ni][r] = 0.f;

    const unsigned short* ga = A  + (size_t)(bm + wave * 16 + lrow) * K + lcol;
    const unsigned short* gb = Bw + (size_t)(bn + wave * 16 + lrow) * K + lcol;
    unsigned short* la = &As[(wave * 16) * 32];   // wave-uniform
    unsigned short* lb = &Bs[(wave * 16) * 32];

    for (int k0 = 0; k0 < K; k0 += 32 * NH) {
        __syncthreads();                          // prev-iter LDS reads done
        #pragma unroll
        for (int hf = 0; hf < NH; ++hf) {
            #pragma unroll
            for (int s = 0; s < BM / 64; ++s)
                gload_lds16(ga + k0 + hf * 32 + (size_t)(s * 64) * K,
                            la + hf * BM * 32 + s * 64 * 32);
            #pragma unroll
            for (int s = 0; s < BN / 64; ++s)
                gload_lds16(gb + k0 + hf * 32 + (size_t)(s * 64) * K,
                            lb + hf * BN * 32 + s * 64 * 32);
        }
        __syncthreads();                          // vmcnt drained: tile visible
        #pragma unroll
        for (int hf = 0; hf < NH; ++hf) {
            s16x8 af[MI], bfv[NI];
            #pragma unroll
            for (int mi = 0; mi < MI; ++mi)
                af[mi] = *(const s16x8*)&As[hf * BM * 32 + (wr * (BM / 2) + mi * 16 + fr) * 32 + kg * 8];
            #pragma unroll
            for (int ni = 0; ni < NI; ++ni)
                bfv[ni] = *(const s16x8*)&Bs[hf * BN * 32 + (wc * (BN / 2) + ni * 16 + fr) * 32 + kg * 8];
            #pragma unroll
            for (int mi = 0; mi < MI; ++mi)
                #pragma unroll
                for (int ni = 0; ni < NI; ++ni)
                    acc[mi][ni] = __builtin_amdgcn_mfma_f32_16x16x32_bf16(af[mi], bfv[ni], acc[mi][ni], 0, 0, 0);
        }
    }

    if (vtr && bn >= 2048) {
        // V n-tile: write transposed, packed over r (4 consecutive t)
        #pragma unroll
        for (int mi = 0; mi < MI; ++mi)
            #pragma unroll
            for (int ni = 0; ni < NI; ++ni) {
                const int nl = (bn - 2048) + wc * (BN / 2) + ni * 16 + fr;
                const int h = nl >> 6, d = nl & 63;
                const int m0 = bm + wr * (BM / 2) + mi * 16 + kg * 4;
                const int b = m0 >> 11, t0 = m0 & (T_ - 1);
                ushort4 u;
                u.x = f2bf(acc[mi][ni][0]); u.y = f2bf(acc[mi][ni][1]);
                u.z = f2bf(acc[mi][ni][2]); u.w = f2bf(acc[mi][ni][3]);
                *(ushort4*)(vtr + ((size_t)(b * H_ + h) * 64 + d) * T_ + t0) = u;
            }
        return;
    }
    Tout* C = (bn < 1024) ? C0 : C1;
    const int nb = bn & 1023;
    #pragma unroll
    for (int mi = 0; mi < MI; ++mi)
        #pragma unroll
        for (int ni = 0; ni < NI; ++ni)
            #pragma unroll
            for (int r = 0; r < 4; ++r) {
                int m = bm + wr * (BM / 2) + mi * 16 + kg * 4 + r;
                int n = nb + wc * (BN / 2) + ni * 16 + fr;
                stv(&C[(size_t)m * 1024 + n], acc[mi][ni][r]);
            }
}

// ---------------------------------------------------------------------------
// MFMA sliding-window attention v4 (validated r11). Block = 64 queries of one
// (b,h). K window [klo2,+192) and V^T window [klo2,+208) staged via
// global_load_lds with XOR chunk swizzle; P reuses the dead Ks region after
// QK^T (50 KB/block -> 3 blocks/CU). o==q in-place safe (wave-private rows).
// ---------------------------------------------------------------------------
__global__ __launch_bounds__(256) void swa_mfma4(const unsigned short* qb,
                                                 const unsigned short* __restrict__ kb,
                                                 const unsigned short* __restrict__ vt,
                                                 unsigned short* ob) {
    __shared__ unsigned short Ks[192 * 64];        // 24 KB; P lives here later
    __shared__ unsigned short Vs[64 * 208];        // 26 KB, swizzled (c<24)
    const int wave = threadIdx.x >> 6;
    const int lane = threadIdx.x & 63;
    const int blk = blockIdx.x;                    // 0..1023
    const int i0b = (blk & 31) * 64;               // block's first query
    const int bh  = blk >> 5;
    const int h = bh & (H_ - 1), b = bh >> 4;
    const int g = lane >> 4, l15 = lane & 15;

    const size_t rowbase = (size_t)b * T_ * D_ + (size_t)h * DH_;
    const int klo2 = (i0b > 128) ? (i0b - 128) : 0;   // <= 1856

    // ---- stage K rows [klo2, +192), XOR-swizzled chunks ----
    {
        const int lr = lane >> 3;                  // 0..7
        const int gc = (lane & 7) ^ lr;            // global chunk to fetch
        const unsigned short* kg0 = kb + rowbase + (size_t)(klo2 + lr) * D_ + gc * 8;
        #pragma unroll
        for (int s = 0; s < 6; ++s) {
            const int i = wave * 6 + s;            // 24 instrs, 8 rows each
            gload_lds16(kg0 + (size_t)(i * 8) * D_, &Ks[i * 8 * 64]);
        }
    }
    // ---- stage V^T rows d=0..63, cols [klo2, +208), 26 chunks/row ----
    {
        const unsigned short* vtb = vt + (size_t)bh * 64 * T_ + klo2;
        #pragma unroll
        for (int s = 0; s < 7; ++s) {
            const int i = s * 4 + wave;            // wave-uniform
            if (i < 26) {
                const int cc = i * 64 + lane;      // flat chunk 0..1663
                const int d  = cc / 26;
                const int sl = cc - d * 26;        // LDS slot 0..25
                const int c  = (sl < 24) ? (sl ^ (d & 7)) : sl;  // global chunk
                gload_lds16(vtb + (size_t)d * T_ + c * 8, &Vs[i * 512]);
            }
        }
    }

    const int i0  = i0b + wave * 16;
    const int klo = (i0 > 128) ? (i0 - 128) : 0;
    const int koff = klo - klo2;                   // 0,16,32,48

    // Q fragments from global (issued before barrier: overlap staging drain)
    const unsigned short* qrow = qb + rowbase + (size_t)(i0 + l15) * D_ + g * 8;
    const s16x8 aq0 = *(const s16x8*)(qrow);
    const s16x8 aq1 = *(const s16x8*)(qrow + 32);

    __syncthreads();                               // K+V windows visible

    // ---- S = Q K^T over 9 key tiles (B-frags from swizzled Ks) ----
    f32x4 sacc[9];
    #pragma unroll
    for (int t = 0; t < 9; ++t)
        #pragma unroll
        for (int r = 0; r < 4; ++r) sacc[t][r] = 0.f;

    #pragma unroll
    for (int t = 0; t < 9; ++t) {
        const int row = koff + t * 16 + l15;       // <= 191
        const int r7 = row & 7;
        s16x8 b0 = *(const s16x8*)&Ks[row * 64 + ((g     ^ r7) * 8)];
        s16x8 b1 = *(const s16x8*)&Ks[row * 64 + (((g+4) ^ r7) * 8)];
        sacc[t] = __builtin_amdgcn_mfma_f32_16x16x32_bf16(aq0, b0, sacc[t], 0, 0, 0);
        sacc[t] = __builtin_amdgcn_mfma_f32_16x16x32_bf16(aq1, b1, sacc[t], 0, 0, 0);
    }

    __syncthreads();                               // Ks dead -> P may reuse it
    unsigned short* Pw = &Ks[wave * (16 * 168)];   // 4 x 5376 B, 16B-aligned
    {   // zero-pad P cols 144..159 (read by last PV k-tile)
        int row = lane >> 2, col = 144 + (lane & 3) * 4;
        *(uint2*)&Pw[row * 168 + col] = make_uint2(0u, 0u);
    }

    // ---- mask + scale + softmax (C/D layout: row g*4+r, col l15) ----
    float mrow[4] = {-1e30f, -1e30f, -1e30f, -1e30f};
    #pragma unroll
    for (int t = 0; t < 9; ++t)
        #pragma unroll
        for (int r = 0; r < 4; ++r) {
            const int j  = klo + t * 16 + l15;
            const int iq = i0 + g * 4 + r;
            const bool valid = (j <= iq) && (j + 128 >= iq);
            const float s = valid ? sacc[t][r] * 0.125f : -1e30f;
            sacc[t][r] = s;
            mrow[r] = fmaxf(mrow[r], s);
        }
    #pragma unroll
    for (int r = 0; r < 4; ++r)
        #pragma unroll
        for (int off = 1; off < 16; off <<= 1)
            mrow[r] = fmaxf(mrow[r], __shfl_xor(mrow[r], off));

    float lrow[4] = {0.f, 0.f, 0.f, 0.f};
    #pragma unroll
    for (int t = 0; t < 9; ++t)
        #pragma unroll
        for (int r = 0; r < 4; ++r) {
            const float p = __expf(sacc[t][r] - mrow[r]);
            sacc[t][r] = p;
            lrow[r] += p;
        }
    #pragma unroll
    for (int r = 0; r < 4; ++r) {
        #pragma unroll
        for (int off = 1; off < 16; off <<= 1)
            lrow[r] += __shfl_xor(lrow[r], off);
    }
    float invl[4];
    #pragma unroll
    for (int r = 0; r < 4; ++r) invl[r] = 1.f / lrow[r];

    // ---- P (bf16) -> per-wave LDS (same-wave write->read, no barrier) ----
    #pragma unroll
    for (int t = 0; t < 9; ++t)
        #pragma unroll
        for (int r = 0; r < 4; ++r)
            Pw[(g * 4 + r) * 168 + t * 16 + l15] = f2bf(sacc[t][r]);

    // ---- O = P V : A = P from LDS, B = V^T rows from swizzled Vs ----
    f32x4 oacc[4];
    #pragma unroll
    for (int nt = 0; nt < 4; ++nt)
        #pragma unroll
        for (int r = 0; r < 4; ++r) oacc[nt][r] = 0.f;

    const int kc0 = koff >> 3;                     // 0,2,4,6
    #pragma unroll
    for (int kt = 0; kt < 5; ++kt) {
        const s16x8 ap = *(const s16x8*)&Pw[l15 * 168 + kt * 32 + g * 8];
        #pragma unroll
        for (int nt = 0; nt < 4; ++nt) {
            const int d = nt * 16 + l15;
            const int c = kc0 + kt * 4 + g;        // global chunk 0..25
            const int sl = (c < 24) ? (c ^ (d & 7)) : c;
            s16x8 bv = *(const s16x8*)&Vs[d * 208 + sl * 8];
            oacc[nt] = __builtin_amdgcn_mfma_f32_16x16x32_bf16(ap, bv, oacc[nt], 0, 0, 0);
        }
    }

    #pragma unroll
    for (int nt = 0; nt < 4; ++nt)
        #pragma unroll
        for (int r = 0; r < 4; ++r) {
            const float val = oacc[nt][r] * invl[r];
            ob[rowbase + (size_t)(i0 + g * 4 + r) * D_ + nt * 16 + l15] = f2bf(val);
        }
}

extern "C" void kernel_launch(void* const* d_in, const int* in_sizes, int n_in,
                              void* d_out, int out_size, void* d_ws, size_t ws_size,
                              hipStream_t stream) {
    const float* x  = (const float*)d_in[0];
    const float* Wq = (const float*)d_in[1];
    const float* Wk = (const float*)d_in[2];
    const float* Wv = (const float*)d_in[3];
    const float* Wo = (const float*)d_in[4];

    const size_t MD = (size_t)M_ * D_;      // 4,194,304
    const size_t WN = (size_t)D_ * D_;      // 1,048,576

    // ws (bf16): xb | Wqb|Wkb|Wvb | Wob | qb  = 24 MB
    unsigned short* wsb = (unsigned short*)d_ws;
    unsigned short* xb  = wsb;
    unsigned short* Wqb = xb + MD;          // Wq|Wk|Wv adjacent = merged B matrix
    unsigned short* Wob = Wqb + 3 * WN;
    unsigned short* qb  = Wob + WN;
    // d_out doubles as vt | kb until the final GEMM overwrites it.
    // vt FIRST: swa's V-window tail over-reads land in kb, never past d_out.
    unsigned short* vt = (unsigned short*)d_out;
    unsigned short* kb = vt + MD;

    conv_bf16<<<8192, 256, 0, stream>>>(x, Wq, Wk, Wv, Wo, wsb);

    // merged QKV projection: N=3072, BN=128 -> 768 blocks (3/CU); V transposed
    gemm_m97<128, 128, 2, unsigned short><<<dim3(24, M_ / 128), 256, 0, stream>>>(
        xb, Wqb, qb, kb, vt, D_);

    swa_mfma4<<<(B_ * H_ * T_) / 64, 256, 0, stream>>>(qb, kb, vt, qb);

    // output projection: N=1024, BM=64, BN=128, BK=128 -> 512 blocks (2/CU)
    gemm_m97<64, 128, 4, float><<<dim3(8, M_ / 64), 256, 0, stream>>>(
        qb, Wob, (float*)d_out, (float*)d_out, nullptr, D_);
}